// Round 3
// baseline (608.117 us; speedup 1.0000x reference)
//
#include <hip/hip_runtime.h>
#include <hip/hip_bf16.h>
#include <stdint.h>

// Problem constants
#define B_  4
#define S_  2048
#define D_  1024
#define H_  16
#define DH_ 64
#define N3_ 3072   // 3*D

typedef __attribute__((ext_vector_type(8))) short  short8;   // 8 bf16 (4 VGPRs)
typedef __attribute__((ext_vector_type(8))) unsigned short ushort8;
typedef __attribute__((ext_vector_type(4))) float  float4v;  // 4 fp32 acc

__device__ __forceinline__ float bf2f(unsigned short u) {
    union { unsigned int i; float f; } c; c.i = ((unsigned int)u) << 16; return c.f;
}
__device__ __forceinline__ unsigned short f2bf(float f) {
    union { float f; unsigned int i; } c; c.f = f;
    unsigned int x = c.i;
    return (unsigned short)((x + 0x7FFFu + ((x >> 16) & 1u)) >> 16);  // RNE
}
__device__ __forceinline__ unsigned short f2bf_hu(float f) {   // half-up (cheap)
    union { float f; unsigned int i; } c; c.f = f;
    return (unsigned short)((c.i + 0x8000u) >> 16);
}

// async global->LDS DMA, 16B per lane; LDS dest = wave-uniform base + lane*16
__device__ __forceinline__ void gll16(const void* g, void* l) {
    __builtin_amdgcn_global_load_lds(
        (const __attribute__((address_space(1))) unsigned int*)g,
        (__attribute__((address_space(3))) unsigned int*)l, 16, 0, 0);
}

// ---------------------------------------------------------------------------
// fp32 -> bf16 elementwise (x). 8 elems/thread.
// ---------------------------------------------------------------------------
__global__ __launch_bounds__(256) void convert_x(
    const float* __restrict__ in, unsigned short* __restrict__ out, int n8)
{
    int g = blockIdx.x * 256 + threadIdx.x;
    if (g >= n8) return;
    const float4* p = (const float4*)(in + (size_t)g * 8);
    float4 a = p[0], b = p[1];
    ushort8 o;
    o[0] = f2bf(a.x); o[1] = f2bf(a.y); o[2] = f2bf(a.z); o[3] = f2bf(a.w);
    o[4] = f2bf(b.x); o[5] = f2bf(b.y); o[6] = f2bf(b.z); o[7] = f2bf(b.w);
    *(ushort8*)(out + (size_t)g * 8) = o;
}

// ---------------------------------------------------------------------------
// fp32 [K][N] -> bf16 [N][K] transpose (weights). 32x32 LDS tile, 256 thr.
// ---------------------------------------------------------------------------
__global__ __launch_bounds__(256) void convert_wT(
    const float* __restrict__ w, unsigned short* __restrict__ wt, int K, int N)
{
    __shared__ float t[32][33];
    const int row = threadIdx.x >> 5;   // 0..7
    const int col = threadIdx.x & 31;   // 0..31
    const int n0 = blockIdx.x * 32;
    const int k0 = blockIdx.y * 32;
#pragma unroll
    for (int i = 0; i < 4; ++i)
        t[row + 8 * i][col] = w[(size_t)(k0 + row + 8 * i) * N + n0 + col];
    __syncthreads();
#pragma unroll
    for (int i = 0; i < 4; ++i)
        wt[(size_t)(n0 + row + 8 * i) * K + k0 + col] = f2bf(t[col][row + 8 * i]);
}

// ---------------------------------------------------------------------------
// bf16 MFMA GEMM: C[M,N] = A[M,K] @ Bt[N,K]^T + bias.
// 128x128 tile, BK=64, 4 waves, each wave 64x64 (4x4 MFMA tiles).
// (unchanged — m97-structure, XOR-swizzled global_load_lds staging)
// MODE 0: scatter to q/k [B][H][S][DH] and vT [B][H][DH][S] bf16 (N=3072).
// MODE 1: fp32 out [M][N] (N=1024).
// ---------------------------------------------------------------------------
template <int MODE>
__global__ __launch_bounds__(256) void gemm_bt(
    const unsigned short* __restrict__ a, const unsigned short* __restrict__ bt,
    const float* __restrict__ bias,
    unsigned short* __restrict__ q, unsigned short* __restrict__ k,
    unsigned short* __restrict__ v, float* __restrict__ out,
    int K, int N)
{
    __shared__ unsigned short As[128][64];   // unpadded: 16 KB each
    __shared__ unsigned short Bs[128][64];

    const int tid  = threadIdx.x;
    const int wave = tid >> 6;
    const int lane = tid & 63;
    const int col  = lane & 15;
    const int quad = lane >> 4;
    const int wm   = (wave & 1) * 64;
    const int wn   = (wave >> 1) * 64;

    const int m0 = blockIdx.y * 128;
    const int n0 = blockIdx.x * 128;

    const int srow0 = wave * 32 + (lane >> 3);
    const int scg   = (lane & 7) ^ (lane >> 3);

    float4v acc[4][4] = {};

    for (int kt = 0; kt < K; kt += 64) {
#pragma unroll
        for (int c = 0; c < 4; ++c) {
            int row = srow0 + c * 8;
            gll16(a  + (size_t)(m0 + row) * K + kt + scg * 8,
                  (char*)As + wave * 4096 + c * 1024);
            gll16(bt + (size_t)(n0 + row) * K + kt + scg * 8,
                  (char*)Bs + wave * 4096 + c * 1024);
        }
        __syncthreads();   // drains vmcnt (incl. global_load_lds)

#pragma unroll
        for (int ks = 0; ks < 64; ks += 32) {
            const int sa = (((ks >> 3) + quad) ^ (col & 7)) * 8;  // swizzled offset
            short8 af[4], bf[4];
#pragma unroll
            for (int mi = 0; mi < 4; ++mi)
                af[mi] = *(const short8*)&As[wm + mi * 16 + col][sa];
#pragma unroll
            for (int ni = 0; ni < 4; ++ni)
                bf[ni] = *(const short8*)&Bs[wn + ni * 16 + col][sa];
#pragma unroll
            for (int mi = 0; mi < 4; ++mi)
#pragma unroll
                for (int ni = 0; ni < 4; ++ni)
                    acc[mi][ni] = __builtin_amdgcn_mfma_f32_16x16x32_bf16(
                        af[mi], bf[ni], acc[mi][ni], 0, 0, 0);
        }
        __syncthreads();
    }

#pragma unroll
    for (int mi = 0; mi < 4; ++mi) {
#pragma unroll
        for (int ni = 0; ni < 4; ++ni) {
            int n = n0 + wn + ni * 16 + col;
            float bv = bias[n];
#pragma unroll
            for (int r = 0; r < 4; ++r) {
                int m = m0 + wm + mi * 16 + quad * 4 + r;
                float val = acc[mi][ni][r] + bv;
                if (MODE == 0) {
                    int which = n >> 10;          // 0=Q 1=K 2=V
                    int h  = (n & 1023) >> 6;
                    int dh = n & 63;
                    int bb = m >> 11;
                    int s  = m & 2047;
                    size_t off;
                    if (which == 2)   // V stored transposed: [b][h][dh][s]
                        off = (((size_t)bb * H_ + h) * DH_ + dh) * S_ + s;
                    else
                        off = (((size_t)bb * H_ + h) * S_ + s) * DH_ + dh;
                    unsigned short* dst = (which == 0) ? q : ((which == 1) ? k : v);
                    dst[off] = f2bf(val);
                } else {
                    out[(size_t)m * N + n] = val;
                }
            }
        }
    }
}

// ---------------------------------------------------------------------------
// Flash-style MFMA attention, v8.
// Post-mortem v6/v7: swapped-QK^T P-path added serialized stall (v7: 195us,
// 2.1M conflicts, both utils DOWN) -> the softmax/P path was never the
// limiter. v5's 39% stall is per-kv-tile FIXED cost (staging drain, 2
// barriers, K/V frag reads). v8 reverts to the byte-exact v5 compute path
// and AMORTIZES: each wave owns TWO 16-row q-blocks (rows q0.., q0+64..).
//  - K/V staging, barriers, Ks/Vt fragment reads: shared (1x per tile)
//  - MFMA per tile: 16 -> 32 (each K/V frag read feeds 4 MFMA, was 2)
//  - grid x: S/64 -> S/128 (1024 blocks, 4/CU, all resident)
//  - Ps doubled -> LDS 32KB (5 blocks/CU capacity >= 4 resident)
//  - launch_bounds(256,4) caps VGPR at 128 to keep 4 blocks/CU
// Fragment layouts (validated): A[m][k]: m=lane&15,k=quad*8+j;
// B[k][n]: n=lane&15,k=quad*8+j; C/D: col(n)=lane&15, row(m)=quad*4+reg.
// P layout (v5, measured 0 conflicts): row rowp=quad*4+r, key k=sub*16+col
// stored at granule (k>>3)^(rowp&7), byte k&7.
// ---------------------------------------------------------------------------
__global__ __launch_bounds__(256, 4) void attn_mfma(
    const unsigned short* __restrict__ q, const unsigned short* __restrict__ k,
    const unsigned short* __restrict__ vT, const int* __restrict__ mask,
    unsigned short* __restrict__ ctx)
{
    __shared__ unsigned short Ks[64][64];         // [key][dh], swizzled granules
    __shared__ unsigned short Vt[64][64];         // [dh][key], swizzled granules
    __shared__ unsigned short Ps[4][2][16][64];   // [wave][qb][row][key], swizzled

    const int tid  = threadIdx.x;
    const int wave = tid >> 6;
    const int lane = tid & 63;
    const int col  = lane & 15;
    const int quad = lane >> 4;

    const int h  = blockIdx.y;
    const int bb = blockIdx.z;
    const int q0 = blockIdx.x * 128 + wave * 16;   // qb0 rows; qb1 = q0+64
    const int kvbase = ((bb * H_ + h) * S_) * DH_;
    const int vtbase = ((bb * H_ + h) * DH_) * S_;

    // Q A-frags for both q-blocks, pre-scaled by 1/sqrt(DH) * log2(e)
    const float SC = 0.18033688011112042f;
    short8 qa[2][2];
#pragma unroll
    for (int qb = 0; qb < 2; ++qb) {
        const unsigned short* qrow = q + kvbase + (q0 + qb * 64 + col) * DH_;
        ushort8 qr0 = *(const ushort8*)(qrow + quad * 8);
        ushort8 qr1 = *(const ushort8*)(qrow + 32 + quad * 8);
#pragma unroll
        for (int j = 0; j < 8; ++j) {
            qa[qb][0][j] = (short)f2bf(bf2f(qr0[j]) * SC);
            qa[qb][1][j] = (short)f2bf(bf2f(qr1[j]) * SC);
        }
    }
    const float MASKED = -1442.6951f;   // -1000*log2(e): exp2 -> exactly 0

    const int* mptr[4];
#pragma unroll
    for (int r = 0; r < 4; ++r)
        mptr[r] = mask + ((size_t)bb * S_ + q0 + quad * 4 + r) * S_ + col;
    const int QB1 = 64 * S_;   // row offset for qb1 in mask (ints)

    // staging geometry (wave pair): rows [sw2*32, sw2*32+32)
    const int sw2   = wave & 1;
    const int srow0 = sw2 * 32 + (lane >> 3);
    const int scg   = (lane & 7) ^ (lane >> 3);
    const int sw0   = (quad ^ (col & 7)) * 8;        // frag offset, k<32
    const int sw1   = ((4 + quad) ^ (col & 7)) * 8;  // k>=32

    float4v oaccA[4] = {}, oaccB[4] = {};
    float rsumA[4] = {0.f, 0.f, 0.f, 0.f};
    float rsumB[4] = {0.f, 0.f, 0.f, 0.f};

    for (int kt = 0; kt < S_ / 64; ++kt) {
        const int key0 = kt * 64;

        // ---- hoist qb0 mask loads (hide behind staging + barrier) ----
        int mk0[4][4];
#pragma unroll
        for (int sub = 0; sub < 4; ++sub)
#pragma unroll
            for (int r = 0; r < 4; ++r)
                mk0[sub][r] = mptr[r][key0 + sub * 16];

        // ---- stage K and V^T via global_load_lds (waves 0,1=K; 2,3=V) ----
#pragma unroll
        for (int c = 0; c < 4; ++c) {
            int r = srow0 + c * 8;
            if (wave < 2)
                gll16(k + kvbase + (key0 + r) * DH_ + scg * 8,
                      (char*)Ks + sw2 * 4096 + c * 1024);
            else
                gll16(vT + vtbase + r * S_ + key0 + scg * 8,
                      (char*)Vt + sw2 * 4096 + c * 1024);
        }
        __syncthreads();

        // ---- QK^T for both q-blocks (K-frags read once, feed 4 MFMA) ----
        float4v scA[4], scB[4];
#pragma unroll
        for (int sub = 0; sub < 4; ++sub) {
            short8 b0 = *(const short8*)&Ks[sub * 16 + col][sw0];
            short8 b1 = *(const short8*)&Ks[sub * 16 + col][sw1];
            float4v t0 = {}, t1 = {};
            t0 = __builtin_amdgcn_mfma_f32_16x16x32_bf16(qa[0][0], b0, t0, 0, 0, 0);
            t0 = __builtin_amdgcn_mfma_f32_16x16x32_bf16(qa[0][1], b1, t0, 0, 0, 0);
            t1 = __builtin_amdgcn_mfma_f32_16x16x32_bf16(qa[1][0], b0, t1, 0, 0, 0);
            t1 = __builtin_amdgcn_mfma_f32_16x16x32_bf16(qa[1][1], b1, t1, 0, 0, 0);
            scA[sub] = t0; scB[sub] = t1;
        }

        // ---- qb1 mask loads (L2-hot; consumed after qb0 softmax) ----
        int mk1[4][4];
#pragma unroll
        for (int sub = 0; sub < 4; ++sub)
#pragma unroll
            for (int r = 0; r < 4; ++r)
                mk1[sub][r] = mptr[r][QB1 + key0 + sub * 16];

        // ---- softmax qb0 -> Ps[wave][0]  (v5 path, 0 conflicts) ----
#pragma unroll
        for (int sub = 0; sub < 4; ++sub)
#pragma unroll
        for (int r = 0; r < 4; ++r) {
            float s = (mk0[sub][r] == 0) ? MASKED : scA[sub][r];
            float p = __builtin_amdgcn_exp2f(s);
            rsumA[r] += p;
            int rowp = quad * 4 + r;
            int sg = (sub * 2 + (col >> 3)) ^ (rowp & 7);
            Ps[wave][0][rowp][sg * 8 + (col & 7)] = f2bf_hu(p);
        }
        // ---- softmax qb1 -> Ps[wave][1] ----
#pragma unroll
        for (int sub = 0; sub < 4; ++sub)
#pragma unroll
        for (int r = 0; r < 4; ++r) {
            float s = (mk1[sub][r] == 0) ? MASKED : scB[sub][r];
            float p = __builtin_amdgcn_exp2f(s);
            rsumB[r] += p;
            int rowp = quad * 4 + r;
            int sg = (sub * 2 + (col >> 3)) ^ (rowp & 7);
            Ps[wave][1][rowp][sg * 8 + (col & 7)] = f2bf_hu(p);
        }
        // no barrier: Ps is wave-private (lgkmcnt ordering suffices)

        // ---- P A-frags for both q-blocks ----
        short8 paA0 = *(const short8*)&Ps[wave][0][col][sw0];
        short8 paA1 = *(const short8*)&Ps[wave][0][col][sw1];
        short8 paB0 = *(const short8*)&Ps[wave][1][col][sw0];
        short8 paB1 = *(const short8*)&Ps[wave][1][col][sw1];

        // ---- PV: V-frags read once, feed 4 MFMA ----
#pragma unroll
        for (int n = 0; n < 4; ++n) {
            short8 vb0 = *(const short8*)&Vt[n * 16 + col][sw0];
            short8 vb1 = *(const short8*)&Vt[n * 16 + col][sw1];
            oaccA[n] = __builtin_amdgcn_mfma_f32_16x16x32_bf16(paA0, vb0, oaccA[n], 0, 0, 0);
            oaccA[n] = __builtin_amdgcn_mfma_f32_16x16x32_bf16(paA1, vb1, oaccA[n], 0, 0, 0);
            oaccB[n] = __builtin_amdgcn_mfma_f32_16x16x32_bf16(paB0, vb0, oaccB[n], 0, 0, 0);
            oaccB[n] = __builtin_amdgcn_mfma_f32_16x16x32_bf16(paB1, vb1, oaccB[n], 0, 0, 0);
        }
        __syncthreads();   // Ks/Vt reads done before restage
    }

    // ---- final row-sum reduction + normalize + store (both q-blocks) ----
    float invA[4], invB[4];
#pragma unroll
    for (int r = 0; r < 4; ++r) {
        float sA = rsumA[r], sB = rsumB[r];
#pragma unroll
        for (int msk = 1; msk < 16; msk <<= 1) {
            sA += __shfl_xor(sA, msk);
            sB += __shfl_xor(sB, msk);
        }
        invA[r] = 1.0f / sA;
        invB[r] = 1.0f / sB;
    }
#pragma unroll
    for (int n = 0; n < 4; ++n)
#pragma unroll
    for (int r = 0; r < 4; ++r) {
        size_t offA = ((size_t)bb * S_ + (q0 + quad * 4 + r)) * D_
                    + h * DH_ + n * 16 + col;
        ctx[offA] = f2bf(oaccA[n][r] * invA[r]);
        size_t offB = ((size_t)bb * S_ + (q0 + 64 + quad * 4 + r)) * D_
                    + h * DH_ + n * 16 + col;
        ctx[offB] = f2bf(oaccB[n][r] * invB[r]);
    }
}

extern "C" void kernel_launch(void* const* d_in, const int* in_sizes, int n_in,
                              void* d_out, int out_size, void* d_ws, size_t ws_size,
                              hipStream_t stream)
{
    const float* x     = (const float*)d_in[0];
    const int*   mask  = (const int*)d_in[1];
    const float* w_qkv = (const float*)d_in[2];
    const float* b_qkv = (const float*)d_in[3];
    const float* w_out = (const float*)d_in[4];
    const float* b_out = (const float*)d_in[5];
    float* out = (float*)d_out;

    unsigned short* ws = (unsigned short*)d_ws;
    const size_t sz = (size_t)B_ * S_ * D_;   // 8,388,608 elements
    unsigned short* q     = ws;
    unsigned short* kk    = ws + sz;
    unsigned short* v     = ws + 2 * sz;      // vT layout [B][H][DH][S]
    unsigned short* ctx   = ws + 3 * sz;
    unsigned short* xbf   = ws + 4 * sz;
    unsigned short* wqkvT = ws + 5 * sz;                       // 3072*1024
    unsigned short* woutT = ws + 5 * sz + (size_t)N3_ * D_;    // 1024*1024

    convert_x<<<(int)(sz / (256 * 8)), 256, 0, stream>>>(x, xbf, (int)(sz / 8));
    convert_wT<<<dim3(N3_ / 32, D_ / 32), 256, 0, stream>>>(w_qkv, wqkvT, D_, N3_);
    convert_wT<<<dim3(D_ / 32, D_ / 32), 256, 0, stream>>>(w_out, woutT, D_, D_);

    gemm_bt<0><<<dim3(N3_ / 128, (B_ * S_) / 128), 256, 0, stream>>>(
        xbf, wqkvT, b_qkv, q, kk, v, nullptr, D_, N3_);

    attn_mfma<<<dim3(S_ / 128, H_, B_), 256, 0, stream>>>(q, kk, v, mask, ctx);

    gemm_bt<1><<<dim3(D_ / 128, (B_ * S_) / 128), 256, 0, stream>>>(
        ctx, woutT, b_out, nullptr, nullptr, nullptr, out, D_, D_);
}

// Round 4
// 419.980 us; speedup vs baseline: 1.4480x; 1.4480x over previous
//
#include <hip/hip_runtime.h>
#include <hip/hip_bf16.h>
#include <stdint.h>

// Problem constants
#define B_  4
#define S_  2048
#define D_  1024
#define H_  16
#define DH_ 64
#define N3_ 3072   // 3*D

typedef __attribute__((ext_vector_type(8))) short  short8;   // 8 bf16 (4 VGPRs)
typedef __attribute__((ext_vector_type(8))) unsigned short ushort8;
typedef __attribute__((ext_vector_type(4))) float  float4v;  // 4 fp32 acc

__device__ __forceinline__ float bf2f(unsigned short u) {
    union { unsigned int i; float f; } c; c.i = ((unsigned int)u) << 16; return c.f;
}
__device__ __forceinline__ unsigned short f2bf(float f) {
    union { float f; unsigned int i; } c; c.f = f;
    unsigned int x = c.i;
    return (unsigned short)((x + 0x7FFFu + ((x >> 16) & 1u)) >> 16);  // RNE
}
__device__ __forceinline__ unsigned short f2bf_hu(float f) {   // half-up (cheap)
    union { float f; unsigned int i; } c; c.f = f;
    return (unsigned short)((c.i + 0x8000u) >> 16);
}

// async global->LDS DMA, 16B per lane; LDS dest = wave-uniform base + lane*16
__device__ __forceinline__ void gll16(const void* g, void* l) {
    __builtin_amdgcn_global_load_lds(
        (const __attribute__((address_space(1))) unsigned int*)g,
        (__attribute__((address_space(3))) unsigned int*)l, 16, 0, 0);
}

// ---------------------------------------------------------------------------
// fp32 -> bf16 elementwise (x). 8 elems/thread.
// ---------------------------------------------------------------------------
__global__ __launch_bounds__(256) void convert_x(
    const float* __restrict__ in, unsigned short* __restrict__ out, int n8)
{
    int g = blockIdx.x * 256 + threadIdx.x;
    if (g >= n8) return;
    const float4* p = (const float4*)(in + (size_t)g * 8);
    float4 a = p[0], b = p[1];
    ushort8 o;
    o[0] = f2bf(a.x); o[1] = f2bf(a.y); o[2] = f2bf(a.z); o[3] = f2bf(a.w);
    o[4] = f2bf(b.x); o[5] = f2bf(b.y); o[6] = f2bf(b.z); o[7] = f2bf(b.w);
    *(ushort8*)(out + (size_t)g * 8) = o;
}

// ---------------------------------------------------------------------------
// fp32 [K][N] -> bf16 [N][K] transpose (weights). 32x32 LDS tile, 256 thr.
// ---------------------------------------------------------------------------
__global__ __launch_bounds__(256) void convert_wT(
    const float* __restrict__ w, unsigned short* __restrict__ wt, int K, int N)
{
    __shared__ float t[32][33];
    const int row = threadIdx.x >> 5;   // 0..7
    const int col = threadIdx.x & 31;   // 0..31
    const int n0 = blockIdx.x * 32;
    const int k0 = blockIdx.y * 32;
#pragma unroll
    for (int i = 0; i < 4; ++i)
        t[row + 8 * i][col] = w[(size_t)(k0 + row + 8 * i) * N + n0 + col];
    __syncthreads();
#pragma unroll
    for (int i = 0; i < 4; ++i)
        wt[(size_t)(n0 + row + 8 * i) * K + k0 + col] = f2bf(t[col][row + 8 * i]);
}

// ---------------------------------------------------------------------------
// bf16 MFMA GEMM: C[M,N] = A[M,K] @ Bt[N,K]^T + bias.
// 128x128 tile, BK=64, 4 waves, each wave 64x64 (4x4 MFMA tiles).
// (unchanged — m97-structure, XOR-swizzled global_load_lds staging)
// MODE 0: scatter to q/k [B][H][S][DH] and vT [B][H][DH][S] bf16 (N=3072).
// MODE 1: fp32 out [M][N] (N=1024).
// ---------------------------------------------------------------------------
template <int MODE>
__global__ __launch_bounds__(256) void gemm_bt(
    const unsigned short* __restrict__ a, const unsigned short* __restrict__ bt,
    const float* __restrict__ bias,
    unsigned short* __restrict__ q, unsigned short* __restrict__ k,
    unsigned short* __restrict__ v, float* __restrict__ out,
    int K, int N)
{
    __shared__ unsigned short As[128][64];   // unpadded: 16 KB each
    __shared__ unsigned short Bs[128][64];

    const int tid  = threadIdx.x;
    const int wave = tid >> 6;
    const int lane = tid & 63;
    const int col  = lane & 15;
    const int quad = lane >> 4;
    const int wm   = (wave & 1) * 64;
    const int wn   = (wave >> 1) * 64;

    const int m0 = blockIdx.y * 128;
    const int n0 = blockIdx.x * 128;

    const int srow0 = wave * 32 + (lane >> 3);
    const int scg   = (lane & 7) ^ (lane >> 3);

    float4v acc[4][4] = {};

    for (int kt = 0; kt < K; kt += 64) {
#pragma unroll
        for (int c = 0; c < 4; ++c) {
            int row = srow0 + c * 8;
            gll16(a  + (size_t)(m0 + row) * K + kt + scg * 8,
                  (char*)As + wave * 4096 + c * 1024);
            gll16(bt + (size_t)(n0 + row) * K + kt + scg * 8,
                  (char*)Bs + wave * 4096 + c * 1024);
        }
        __syncthreads();   // drains vmcnt (incl. global_load_lds)

#pragma unroll
        for (int ks = 0; ks < 64; ks += 32) {
            const int sa = (((ks >> 3) + quad) ^ (col & 7)) * 8;  // swizzled offset
            short8 af[4], bf[4];
#pragma unroll
            for (int mi = 0; mi < 4; ++mi)
                af[mi] = *(const short8*)&As[wm + mi * 16 + col][sa];
#pragma unroll
            for (int ni = 0; ni < 4; ++ni)
                bf[ni] = *(const short8*)&Bs[wn + ni * 16 + col][sa];
#pragma unroll
            for (int mi = 0; mi < 4; ++mi)
#pragma unroll
                for (int ni = 0; ni < 4; ++ni)
                    acc[mi][ni] = __builtin_amdgcn_mfma_f32_16x16x32_bf16(
                        af[mi], bf[ni], acc[mi][ni], 0, 0, 0);
        }
        __syncthreads();
    }

#pragma unroll
    for (int mi = 0; mi < 4; ++mi) {
#pragma unroll
        for (int ni = 0; ni < 4; ++ni) {
            int n = n0 + wn + ni * 16 + col;
            float bv = bias[n];
#pragma unroll
            for (int r = 0; r < 4; ++r) {
                int m = m0 + wm + mi * 16 + quad * 4 + r;
                float val = acc[mi][ni][r] + bv;
                if (MODE == 0) {
                    int which = n >> 10;          // 0=Q 1=K 2=V
                    int h  = (n & 1023) >> 6;
                    int dh = n & 63;
                    int bb = m >> 11;
                    int s  = m & 2047;
                    size_t off;
                    if (which == 2)   // V stored transposed: [b][h][dh][s]
                        off = (((size_t)bb * H_ + h) * DH_ + dh) * S_ + s;
                    else
                        off = (((size_t)bb * H_ + h) * S_ + s) * DH_ + dh;
                    unsigned short* dst = (which == 0) ? q : ((which == 1) ? k : v);
                    dst[off] = f2bf(val);
                } else {
                    out[(size_t)m * N + n] = val;
                }
            }
        }
    }
}

// ---------------------------------------------------------------------------
// Flash-style MFMA attention, v9.
// Post-mortem v8 (382us): WRITE_SIZE 16->450MB, FETCH 180->750MB = register
// SPILL to scratch (demand ~150 vs launch_bounds(256,4) cap 128). MFMA
// cycles were conserved (v5 0.172*164 = v8 0.072*382) -> the 2-qb-per-wave
// amortization did the same matrix work; scratch I/O killed it.
// v9 = v8 structure with peak pressure cut below the cap:
//  - QK^T in TWO passes: qb0 (read K-frags, MFMA, softmax -> Ps[0]), then
//    qb1 (RE-READ K-frags, reuse the same 16 score regs, softmax -> Ps[1]).
//    Only one 16-reg score array live at any time (+8 ds_read/tile/wave).
//  - mk1 mask loads issued after pass-1 MFMA (never co-live with mk0
//    through QK^T).
//  - PV keeps shared V-frags (pa 16 + vb 8 + oacc 32 live ~ 87 regs).
// Peak estimate ~108 < 128. LDS 32KB -> 4 blocks/CU, grid = exactly 4/CU.
// Fragment layouts (validated): A[m][k]: m=lane&15,k=quad*8+j;
// B[k][n]: n=lane&15,k=quad*8+j; C/D: col(n)=lane&15, row(m)=quad*4+reg.
// P layout (v5, measured 0 conflicts): row rowp=quad*4+r, key k=sub*16+col
// stored at granule (k>>3)^(rowp&7), byte k&7.
// ---------------------------------------------------------------------------
__global__ __launch_bounds__(256, 4) void attn_mfma(
    const unsigned short* __restrict__ q, const unsigned short* __restrict__ k,
    const unsigned short* __restrict__ vT, const int* __restrict__ mask,
    unsigned short* __restrict__ ctx)
{
    __shared__ unsigned short Ks[64][64];         // [key][dh], swizzled granules
    __shared__ unsigned short Vt[64][64];         // [dh][key], swizzled granules
    __shared__ unsigned short Ps[4][2][16][64];   // [wave][qb][row][key], swizzled

    const int tid  = threadIdx.x;
    const int wave = tid >> 6;
    const int lane = tid & 63;
    const int col  = lane & 15;
    const int quad = lane >> 4;

    const int h  = blockIdx.y;
    const int bb = blockIdx.z;
    const int q0 = blockIdx.x * 128 + wave * 16;   // qb0 rows; qb1 = q0+64
    const int kvbase = ((bb * H_ + h) * S_) * DH_;
    const int vtbase = ((bb * H_ + h) * DH_) * S_;

    // Q A-frags for both q-blocks, pre-scaled by 1/sqrt(DH) * log2(e)
    const float SC = 0.18033688011112042f;
    short8 qa[2][2];
#pragma unroll
    for (int qb = 0; qb < 2; ++qb) {
        const unsigned short* qrow = q + kvbase + (q0 + qb * 64 + col) * DH_;
        ushort8 qr0 = *(const ushort8*)(qrow + quad * 8);
        ushort8 qr1 = *(const ushort8*)(qrow + 32 + quad * 8);
#pragma unroll
        for (int j = 0; j < 8; ++j) {
            qa[qb][0][j] = (short)f2bf(bf2f(qr0[j]) * SC);
            qa[qb][1][j] = (short)f2bf(bf2f(qr1[j]) * SC);
        }
    }
    const float MASKED = -1442.6951f;   // -1000*log2(e): exp2 -> exactly 0

    // mask base: lane (col,quad), row qrow = q0 + quad*4 + r, key col + ...
    const int* mrow = mask + ((size_t)bb * S_ + q0 + quad * 4) * S_ + col;
    const int QB1 = 64 * S_;   // row offset for qb1 in mask (ints)

    // staging geometry (wave pair): rows [sw2*32, sw2*32+32)
    const int sw2   = wave & 1;
    const int srow0 = sw2 * 32 + (lane >> 3);
    const int scg   = (lane & 7) ^ (lane >> 3);
    const int sw0   = (quad ^ (col & 7)) * 8;        // frag offset, k<32
    const int sw1   = ((4 + quad) ^ (col & 7)) * 8;  // k>=32

    float4v oaccA[4] = {}, oaccB[4] = {};
    float rsumA[4] = {0.f, 0.f, 0.f, 0.f};
    float rsumB[4] = {0.f, 0.f, 0.f, 0.f};

    for (int kt = 0; kt < S_ / 64; ++kt) {
        const int key0 = kt * 64;

        // ---- hoist qb0 mask loads (hide behind staging + barrier) ----
        int mk[4][4];
#pragma unroll
        for (int sub = 0; sub < 4; ++sub)
#pragma unroll
            for (int r = 0; r < 4; ++r)
                mk[sub][r] = mrow[(size_t)r * S_ + key0 + sub * 16];

        // ---- stage K and V^T via global_load_lds (waves 0,1=K; 2,3=V) ----
#pragma unroll
        for (int c = 0; c < 4; ++c) {
            int r = srow0 + c * 8;
            if (wave < 2)
                gll16(k + kvbase + (key0 + r) * DH_ + scg * 8,
                      (char*)Ks + sw2 * 4096 + c * 1024);
            else
                gll16(vT + vtbase + r * S_ + key0 + scg * 8,
                      (char*)Vt + sw2 * 4096 + c * 1024);
        }
        __syncthreads();

        // ============ pass 1: qb0 ============
        float4v sc[4];
#pragma unroll
        for (int sub = 0; sub < 4; ++sub) {
            short8 b0 = *(const short8*)&Ks[sub * 16 + col][sw0];
            short8 b1 = *(const short8*)&Ks[sub * 16 + col][sw1];
            float4v t = {};
            t = __builtin_amdgcn_mfma_f32_16x16x32_bf16(qa[0][0], b0, t, 0, 0, 0);
            t = __builtin_amdgcn_mfma_f32_16x16x32_bf16(qa[0][1], b1, t, 0, 0, 0);
            sc[sub] = t;
        }
        // softmax qb0 -> Ps[wave][0] (v5 path, 0 conflicts); frees sc
#pragma unroll
        for (int sub = 0; sub < 4; ++sub)
#pragma unroll
        for (int r = 0; r < 4; ++r) {
            float s = (mk[sub][r] == 0) ? MASKED : sc[sub][r];
            float p = __builtin_amdgcn_exp2f(s);
            rsumA[r] += p;
            int rowp = quad * 4 + r;
            int sg = (sub * 2 + (col >> 3)) ^ (rowp & 7);
            Ps[wave][0][rowp][sg * 8 + (col & 7)] = f2bf_hu(p);
        }

        // ---- qb1 mask loads (L2-hot), reuse mk regs ----
#pragma unroll
        for (int sub = 0; sub < 4; ++sub)
#pragma unroll
            for (int r = 0; r < 4; ++r)
                mk[sub][r] = mrow[(size_t)r * S_ + QB1 + key0 + sub * 16];

        // ============ pass 2: qb1 (re-read K-frags, reuse sc regs) ============
#pragma unroll
        for (int sub = 0; sub < 4; ++sub) {
            short8 b0 = *(const short8*)&Ks[sub * 16 + col][sw0];
            short8 b1 = *(const short8*)&Ks[sub * 16 + col][sw1];
            float4v t = {};
            t = __builtin_amdgcn_mfma_f32_16x16x32_bf16(qa[1][0], b0, t, 0, 0, 0);
            t = __builtin_amdgcn_mfma_f32_16x16x32_bf16(qa[1][1], b1, t, 0, 0, 0);
            sc[sub] = t;
        }
#pragma unroll
        for (int sub = 0; sub < 4; ++sub)
#pragma unroll
        for (int r = 0; r < 4; ++r) {
            float s = (mk[sub][r] == 0) ? MASKED : sc[sub][r];
            float p = __builtin_amdgcn_exp2f(s);
            rsumB[r] += p;
            int rowp = quad * 4 + r;
            int sg = (sub * 2 + (col >> 3)) ^ (rowp & 7);
            Ps[wave][1][rowp][sg * 8 + (col & 7)] = f2bf_hu(p);
        }
        // no barrier: Ps is wave-private (wave DS ops are in-order)

        // ---- P A-frags for both q-blocks ----
        short8 paA0 = *(const short8*)&Ps[wave][0][col][sw0];
        short8 paA1 = *(const short8*)&Ps[wave][0][col][sw1];
        short8 paB0 = *(const short8*)&Ps[wave][1][col][sw0];
        short8 paB1 = *(const short8*)&Ps[wave][1][col][sw1];

        // ---- PV: V-frags read once, feed 4 MFMA ----
#pragma unroll
        for (int n = 0; n < 4; ++n) {
            short8 vb0 = *(const short8*)&Vt[n * 16 + col][sw0];
            short8 vb1 = *(const short8*)&Vt[n * 16 + col][sw1];
            oaccA[n] = __builtin_amdgcn_mfma_f32_16x16x32_bf16(paA0, vb0, oaccA[n], 0, 0, 0);
            oaccA[n] = __builtin_amdgcn_mfma_f32_16x16x32_bf16(paA1, vb1, oaccA[n], 0, 0, 0);
            oaccB[n] = __builtin_amdgcn_mfma_f32_16x16x32_bf16(paB0, vb0, oaccB[n], 0, 0, 0);
            oaccB[n] = __builtin_amdgcn_mfma_f32_16x16x32_bf16(paB1, vb1, oaccB[n], 0, 0, 0);
        }
        __syncthreads();   // Ks/Vt reads done before restage
    }

    // ---- final row-sum reduction + normalize + store (both q-blocks) ----
    float invA[4], invB[4];
#pragma unroll
    for (int r = 0; r < 4; ++r) {
        float sA = rsumA[r], sB = rsumB[r];
#pragma unroll
        for (int msk = 1; msk < 16; msk <<= 1) {
            sA += __shfl_xor(sA, msk);
            sB += __shfl_xor(sB, msk);
        }
        invA[r] = 1.0f / sA;
        invB[r] = 1.0f / sB;
    }
#pragma unroll
    for (int n = 0; n < 4; ++n)
#pragma unroll
    for (int r = 0; r < 4; ++r) {
        size_t offA = ((size_t)bb * S_ + (q0 + quad * 4 + r)) * D_
                    + h * DH_ + n * 16 + col;
        ctx[offA] = f2bf(oaccA[n][r] * invA[r]);
        size_t offB = ((size_t)bb * S_ + (q0 + 64 + quad * 4 + r)) * D_
                    + h * DH_ + n * 16 + col;
        ctx[offB] = f2bf(oaccB[n][r] * invB[r]);
    }
}

extern "C" void kernel_launch(void* const* d_in, const int* in_sizes, int n_in,
                              void* d_out, int out_size, void* d_ws, size_t ws_size,
                              hipStream_t stream)
{
    const float* x     = (const float*)d_in[0];
    const int*   mask  = (const int*)d_in[1];
    const float* w_qkv = (const float*)d_in[2];
    const float* b_qkv = (const float*)d_in[3];
    const float* w_out = (const float*)d_in[4];
    const float* b_out = (const float*)d_in[5];
    float* out = (float*)d_out;

    unsigned short* ws = (unsigned short*)d_ws;
    const size_t sz = (size_t)B_ * S_ * D_;   // 8,388,608 elements
    unsigned short* q     = ws;
    unsigned short* kk    = ws + sz;
    unsigned short* v     = ws + 2 * sz;      // vT layout [B][H][DH][S]
    unsigned short* ctx   = ws + 3 * sz;
    unsigned short* xbf   = ws + 4 * sz;
    unsigned short* wqkvT = ws + 5 * sz;                       // 3072*1024
    unsigned short* woutT = ws + 5 * sz + (size_t)N3_ * D_;    // 1024*1024

    convert_x<<<(int)(sz / (256 * 8)), 256, 0, stream>>>(x, xbf, (int)(sz / 8));
    convert_wT<<<dim3(N3_ / 32, D_ / 32), 256, 0, stream>>>(w_qkv, wqkvT, D_, N3_);
    convert_wT<<<dim3(D_ / 32, D_ / 32), 256, 0, stream>>>(w_out, woutT, D_, D_);

    gemm_bt<0><<<dim3(N3_ / 128, (B_ * S_) / 128), 256, 0, stream>>>(
        xbf, wqkvT, b_qkv, q, kk, v, nullptr, D_, N3_);

    attn_mfma<<<dim3(S_ / 128, H_, B_), 256, 0, stream>>>(q, kk, v, mask, ctx);

    gemm_bt<1><<<dim3(D_ / 128, (B_ * S_) / 128), 256, 0, stream>>>(
        ctx, woutT, b_out, nullptr, nullptr, nullptr, out, D_, D_);
}

// Round 6
// 370.782 us; speedup vs baseline: 1.6401x; 1.1327x over previous
//
#include <hip/hip_runtime.h>
#include <hip/hip_bf16.h>
#include <stdint.h>

// Problem constants
#define B_  4
#define S_  2048
#define D_  1024
#define H_  16
#define DH_ 64
#define N3_ 3072   // 3*D

typedef __attribute__((ext_vector_type(8))) short  short8;   // 8 bf16 (4 VGPRs)
typedef __attribute__((ext_vector_type(8))) unsigned short ushort8;
typedef __attribute__((ext_vector_type(4))) float  float4v;  // 4 fp32 acc

__device__ __forceinline__ float bf2f(unsigned short u) {
    union { unsigned int i; float f; } c; c.i = ((unsigned int)u) << 16; return c.f;
}
__device__ __forceinline__ unsigned short f2bf(float f) {
    union { float f; unsigned int i; } c; c.f = f;
    unsigned int x = c.i;
    return (unsigned short)((x + 0x7FFFu + ((x >> 16) & 1u)) >> 16);  // RNE
}
__device__ __forceinline__ unsigned short f2bf_hu(float f) {   // half-up (cheap)
    union { float f; unsigned int i; } c; c.f = f;
    return (unsigned short)((c.i + 0x8000u) >> 16);
}

// async global->LDS DMA, 16B per lane; LDS dest = wave-uniform base + lane*16
__device__ __forceinline__ void gll16(const void* g, void* l) {
    __builtin_amdgcn_global_load_lds(
        (const __attribute__((address_space(1))) unsigned int*)g,
        (__attribute__((address_space(3))) unsigned int*)l, 16, 0, 0);
}

// ---------------------------------------------------------------------------
// fp32 -> bf16 elementwise (x). 8 elems/thread.
// ---------------------------------------------------------------------------
__global__ __launch_bounds__(256) void convert_x(
    const float* __restrict__ in, unsigned short* __restrict__ out, int n8)
{
    int g = blockIdx.x * 256 + threadIdx.x;
    if (g >= n8) return;
    const float4* p = (const float4*)(in + (size_t)g * 8);
    float4 a = p[0], b = p[1];
    ushort8 o;
    o[0] = f2bf(a.x); o[1] = f2bf(a.y); o[2] = f2bf(a.z); o[3] = f2bf(a.w);
    o[4] = f2bf(b.x); o[5] = f2bf(b.y); o[6] = f2bf(b.z); o[7] = f2bf(b.w);
    *(ushort8*)(out + (size_t)g * 8) = o;
}

// ---------------------------------------------------------------------------
// fp32 [K][N] -> bf16 [N][K] transpose (weights). 32x32 LDS tile, 256 thr.
// ---------------------------------------------------------------------------
__global__ __launch_bounds__(256) void convert_wT(
    const float* __restrict__ w, unsigned short* __restrict__ wt, int K, int N)
{
    __shared__ float t[32][33];
    const int row = threadIdx.x >> 5;   // 0..7
    const int col = threadIdx.x & 31;   // 0..31
    const int n0 = blockIdx.x * 32;
    const int k0 = blockIdx.y * 32;
#pragma unroll
    for (int i = 0; i < 4; ++i)
        t[row + 8 * i][col] = w[(size_t)(k0 + row + 8 * i) * N + n0 + col];
    __syncthreads();
#pragma unroll
    for (int i = 0; i < 4; ++i)
        wt[(size_t)(n0 + row + 8 * i) * K + k0 + col] = f2bf(t[col][row + 8 * i]);
}

// ---------------------------------------------------------------------------
// bf16 MFMA GEMM: C[M,N] = A[M,K] @ Bt[N,K]^T + bias.
// 128x128 tile, BK=64, 4 waves, each wave 64x64 (4x4 MFMA tiles).
// Main loop unchanged (m97-structure, XOR-swizzled global_load_lds staging).
// MODE 0: scatter to q/k [B][H][S][DH] bf16; V via per-wave LDS transpose
//         then COALESCED [b][h][dh][s] dwordx4 stores (v10: was a 16-line
//         2B scatter per store instr = 1024 transactions/wave).
// MODE 1: fp32 out [M][N] (N=1024).
// ---------------------------------------------------------------------------
template <int MODE>
__global__ __launch_bounds__(256) void gemm_bt(
    const unsigned short* __restrict__ a, const unsigned short* __restrict__ bt,
    const float* __restrict__ bias,
    unsigned short* __restrict__ q, unsigned short* __restrict__ k,
    unsigned short* __restrict__ v, float* __restrict__ out,
    int K, int N)
{
    __shared__ unsigned short As[128][64];   // unpadded: 16 KB each
    __shared__ unsigned short Bs[128][64];

    const int tid  = threadIdx.x;
    const int wave = tid >> 6;
    const int lane = tid & 63;
    const int col  = lane & 15;
    const int quad = lane >> 4;
    const int wm   = (wave & 1) * 64;
    const int wn   = (wave >> 1) * 64;

    const int m0 = blockIdx.y * 128;
    const int n0 = blockIdx.x * 128;

    const int srow0 = wave * 32 + (lane >> 3);
    const int scg   = (lane & 7) ^ (lane >> 3);

    float4v acc[4][4] = {};

    for (int kt = 0; kt < K; kt += 64) {
#pragma unroll
        for (int c = 0; c < 4; ++c) {
            int row = srow0 + c * 8;
            gll16(a  + (size_t)(m0 + row) * K + kt + scg * 8,
                  (char*)As + wave * 4096 + c * 1024);
            gll16(bt + (size_t)(n0 + row) * K + kt + scg * 8,
                  (char*)Bs + wave * 4096 + c * 1024);
        }
        __syncthreads();   // drains vmcnt (incl. global_load_lds)

#pragma unroll
        for (int ks = 0; ks < 64; ks += 32) {
            const int sa = (((ks >> 3) + quad) ^ (col & 7)) * 8;  // swizzled offset
            short8 af[4], bf[4];
#pragma unroll
            for (int mi = 0; mi < 4; ++mi)
                af[mi] = *(const short8*)&As[wm + mi * 16 + col][sa];
#pragma unroll
            for (int ni = 0; ni < 4; ++ni)
                bf[ni] = *(const short8*)&Bs[wn + ni * 16 + col][sa];
#pragma unroll
            for (int mi = 0; mi < 4; ++mi)
#pragma unroll
                for (int ni = 0; ni < 4; ++ni)
                    acc[mi][ni] = __builtin_amdgcn_mfma_f32_16x16x32_bf16(
                        af[mi], bf[ni], acc[mi][ni], 0, 0, 0);
        }
        __syncthreads();
    }
    // After the final barrier, no wave touches As/Bs again -> reusable.

    if (MODE == 0) {
        // Per-wave uniform output mapping: n-span = [n0+wn, n0+wn+64),
        // 64-aligned -> which/h uniform; m-span -> bb uniform, s0 base.
        const int nw    = n0 + wn;
        const int which = nw >> 10;            // 0=Q 1=K 2=V
        const int hw    = (nw & 1023) >> 6;
        const int bbw   = (m0 + wm) >> 11;
        const int s0    = (m0 + wm) & 2047;

        if (which == 2) {
            // ---- V: LDS-transpose to [dh][s], then coalesced wide stores ----
            // Wave-private 8KB region carved from As/Bs (free after k-loop).
            char* W = (wave < 2) ? ((char*)As + wave * 8192)
                                 : ((char*)Bs + (wave - 2) * 8192);
            // write: row dh (128B), 8B granule g = s_local>>2, XOR-swizzled
#pragma unroll
            for (int ni = 0; ni < 4; ++ni) {
                const int dh = ni * 16 + col;
                const float bv = bias[nw + ni * 16 + col];
#pragma unroll
                for (int mi = 0; mi < 4; ++mi) {
                    unsigned short e0 = f2bf(acc[mi][ni][0] + bv);
                    unsigned short e1 = f2bf(acc[mi][ni][1] + bv);
                    unsigned short e2 = f2bf(acc[mi][ni][2] + bv);
                    unsigned short e3 = f2bf(acc[mi][ni][3] + bv);
                    uint2 pk;
                    pk.x = ((unsigned int)e1 << 16) | e0;
                    pk.y = ((unsigned int)e3 << 16) | e2;
                    int g = mi * 4 + quad;   // s_local granule (s=mi*16+quad*4+r)
                    *(uint2*)(W + dh * 128 + ((g ^ (dh & 7)) * 8)) = pk;
                }
            }
            // wave-private region: in-wave lgkmcnt ordering suffices, no barrier
#pragma unroll
            for (int it = 0; it < 2; ++it) {
                const int dhr  = (lane >> 1) + it * 32;   // row 0..63
                const int half = lane & 1;                // 64B half of row
                uint2 gr[8];
#pragma unroll
                for (int j = 0; j < 8; ++j)
                    gr[j] = *(const uint2*)(W + dhr * 128 +
                              ((((half << 3) + j) ^ (dhr & 7)) * 8));
                unsigned short* dst = v + (((size_t)bbw * H_ + hw) * DH_ + dhr) * S_
                                        + s0 + half * 32;
                uint4 o0 = {gr[0].x, gr[0].y, gr[1].x, gr[1].y};
                uint4 o1 = {gr[2].x, gr[2].y, gr[3].x, gr[3].y};
                uint4 o2 = {gr[4].x, gr[4].y, gr[5].x, gr[5].y};
                uint4 o3 = {gr[6].x, gr[6].y, gr[7].x, gr[7].y};
                ((uint4*)dst)[0] = o0;
                ((uint4*)dst)[1] = o1;
                ((uint4*)dst)[2] = o2;
                ((uint4*)dst)[3] = o3;
            }
        } else {
            // ---- Q/K: [b][h][s][dh] — 32B-contiguous per quad-row ----
            unsigned short* dstb = (which == 0) ? q : k;
#pragma unroll
            for (int ni = 0; ni < 4; ++ni) {
                const int dh = ni * 16 + col;
                const float bv = bias[nw + ni * 16 + col];
#pragma unroll
                for (int mi = 0; mi < 4; ++mi)
#pragma unroll
                    for (int r = 0; r < 4; ++r) {
                        int s = s0 + mi * 16 + quad * 4 + r;
                        dstb[(((size_t)bbw * H_ + hw) * S_ + s) * DH_ + dh] =
                            f2bf(acc[mi][ni][r] + bv);
                    }
            }
        }
    } else {
#pragma unroll
        for (int mi = 0; mi < 4; ++mi)
#pragma unroll
            for (int ni = 0; ni < 4; ++ni) {
                int n = n0 + wn + ni * 16 + col;
                float bv = bias[n];
#pragma unroll
                for (int r = 0; r < 4; ++r) {
                    int m = m0 + wm + mi * 16 + quad * 4 + r;
                    out[(size_t)m * N + n] = acc[mi][ni][r] + bv;
                }
            }
    }
}

// ---------------------------------------------------------------------------
// Flash-style MFMA attention, v5 (EXACT revert — measured 164 us, 0 bank
// conflicts, 6 blocks/CU, MfmaUtil 17.2 / VALUBusy 43.8).
// Rounds 1-4 post-mortem: dbuf (-2 blocks/CU), swapped-QK^T P-path (+2.1M
// conflicts), and 2x q-rows/wave (spill, then -TLP) ALL lost to this
// structure. v5 is the local optimum; attn work stops here.
// ---------------------------------------------------------------------------
__global__ __launch_bounds__(256) void attn_mfma(
    const unsigned short* __restrict__ q, const unsigned short* __restrict__ k,
    const unsigned short* __restrict__ vT, const int* __restrict__ mask,
    unsigned short* __restrict__ ctx)
{
    __shared__ unsigned short Ks[64][64];      // [key][dh], swizzled granules
    __shared__ unsigned short Vt[64][64];      // [dh][key], swizzled granules
    __shared__ unsigned short Ps[4][16][64];   // per-wave P, swizzled granules

    const int tid  = threadIdx.x;
    const int wave = tid >> 6;
    const int lane = tid & 63;
    const int col  = lane & 15;
    const int quad = lane >> 4;

    const int h  = blockIdx.y;
    const int bb = blockIdx.z;
    const int q0 = blockIdx.x * 64 + wave * 16;
    const int kvbase = ((bb * H_ + h) * S_) * DH_;
    const int vtbase = ((bb * H_ + h) * DH_) * S_;

    // Q A-frags, pre-scaled by 1/sqrt(DH) * log2(e)
    const float SC = 0.18033688011112042f;
    const unsigned short* qrow = q + kvbase + (q0 + col) * DH_;
    ushort8 qr0 = *(const ushort8*)(qrow + quad * 8);
    ushort8 qr1 = *(const ushort8*)(qrow + 32 + quad * 8);
    short8 qa0, qa1;
#pragma unroll
    for (int j = 0; j < 8; ++j) {
        qa0[j] = (short)f2bf(bf2f(qr0[j]) * SC);
        qa1[j] = (short)f2bf(bf2f(qr1[j]) * SC);
    }
    const float MASKED = -1442.6951f;   // -1000*log2(e): exp2 -> exactly 0

    const int* mptr[4];
#pragma unroll
    for (int r = 0; r < 4; ++r)
        mptr[r] = mask + (bb * S_ + q0 + quad * 4 + r) * S_ + col;

    // staging geometry (per half-wave-pair): rows [sw2*32, sw2*32+32)
    const int sw2   = wave & 1;
    const int srow0 = sw2 * 32 + (lane >> 3);
    const int scg   = (lane & 7) ^ (lane >> 3);
    const int sw0   = (quad ^ (col & 7)) * 8;        // swizzled frag offset, k<32
    const int sw1   = ((4 + quad) ^ (col & 7)) * 8;  // k>=32

    float4v oacc[4] = {};
    float rsum[4] = {0.f, 0.f, 0.f, 0.f};

    for (int kt = 0; kt < S_ / 64; ++kt) {
        const int key0 = kt * 64;

        // ---- hoist mask loads (latency hides behind staging + barrier) ----
        int mk[4][4];
#pragma unroll
        for (int sub = 0; sub < 4; ++sub)
#pragma unroll
            for (int r = 0; r < 4; ++r)
                mk[sub][r] = mptr[r][key0 + sub * 16];

        // ---- stage K and V^T via global_load_lds (waves 0,1=K; 2,3=V) ----
#pragma unroll
        for (int c = 0; c < 4; ++c) {
            int r = srow0 + c * 8;
            if (wave < 2)
                gll16(k + kvbase + (key0 + r) * DH_ + scg * 8,
                      (char*)Ks + sw2 * 4096 + c * 1024);
            else
                gll16(vT + vtbase + r * S_ + key0 + scg * 8,
                      (char*)Vt + sw2 * 4096 + c * 1024);
        }
        __syncthreads();

        // ---- QK^T (scores in exp2 domain) ----
        float4v sc[4];
#pragma unroll
        for (int sub = 0; sub < 4; ++sub) {
            short8 b0 = *(const short8*)&Ks[sub * 16 + col][sw0];
            short8 b1 = *(const short8*)&Ks[sub * 16 + col][sw1];
            float4v acs = {};
            acs = __builtin_amdgcn_mfma_f32_16x16x32_bf16(qa0, b0, acs, 0, 0, 0);
            acs = __builtin_amdgcn_mfma_f32_16x16x32_bf16(qa1, b1, acs, 0, 0, 0);
            sc[sub] = acs;
        }

        // ---- mask + exp2 + row-sum accumulate + pack P (swizzled) ----
#pragma unroll
        for (int sub = 0; sub < 4; ++sub)
#pragma unroll
        for (int r = 0; r < 4; ++r) {
            float s = (mk[sub][r] == 0) ? MASKED : sc[sub][r];
            float p = __builtin_amdgcn_exp2f(s);
            rsum[r] += p;
            int rowp = quad * 4 + r;
            int sg = (sub * 2 + (col >> 3)) ^ (rowp & 7);
            Ps[wave][rowp][sg * 8 + (col & 7)] = f2bf_hu(p);
        }
        // no barrier: Ps is wave-private (lgkmcnt ordering suffices)

        // ---- PV: O(16x64) += P(16x64) * V(64x64) ----
        short8 pa0 = *(const short8*)&Ps[wave][col][sw0];
        short8 pa1 = *(const short8*)&Ps[wave][col][sw1];
#pragma unroll
        for (int n = 0; n < 4; ++n) {
            short8 vb0 = *(const short8*)&Vt[n * 16 + col][sw0];
            short8 vb1 = *(const short8*)&Vt[n * 16 + col][sw1];
            oacc[n] = __builtin_amdgcn_mfma_f32_16x16x32_bf16(pa0, vb0, oacc[n], 0, 0, 0);
            oacc[n] = __builtin_amdgcn_mfma_f32_16x16x32_bf16(pa1, vb1, oacc[n], 0, 0, 0);
        }
        __syncthreads();   // Ks/Vt reads done before restage
    }

    // ---- final row-sum reduction + normalize + store ----
    float inv[4];
#pragma unroll
    for (int r = 0; r < 4; ++r) {
        float s = rsum[r];
#pragma unroll
        for (int msk = 1; msk < 16; msk <<= 1)
            s += __shfl_xor(s, msk);
        inv[r] = 1.0f / s;
    }
#pragma unroll
    for (int n = 0; n < 4; ++n)
#pragma unroll
    for (int r = 0; r < 4; ++r) {
        size_t off = ((size_t)bb * S_ + (q0 + quad * 4 + r)) * D_
                   + h * DH_ + n * 16 + col;
        ctx[off] = f2bf(oacc[n][r] * inv[r]);
    }
}

extern "C" void kernel_launch(void* const* d_in, const int* in_sizes, int n_in,
                              void* d_out, int out_size, void* d_ws, size_t ws_size,
                              hipStream_t stream)
{
    const float* x     = (const float*)d_in[0];
    const int*   mask  = (const int*)d_in[1];
    const float* w_qkv = (const float*)d_in[2];
    const float* b_qkv = (const float*)d_in[3];
    const float* w_out = (const float*)d_in[4];
    const float* b_out = (const float*)d_in[5];
    float* out = (float*)d_out;

    unsigned short* ws = (unsigned short*)d_ws;
    const size_t sz = (size_t)B_ * S_ * D_;   // 8,388,608 elements
    unsigned short* q     = ws;
    unsigned short* kk    = ws + sz;
    unsigned short* v     = ws + 2 * sz;      // vT layout [B][H][DH][S]
    unsigned short* ctx   = ws + 3 * sz;
    unsigned short* xbf   = ws + 4 * sz;
    unsigned short* wqkvT = ws + 5 * sz;                       // 3072*1024
    unsigned short* woutT = ws + 5 * sz + (size_t)N3_ * D_;    // 1024*1024

    convert_x<<<(int)(sz / (256 * 8)), 256, 0, stream>>>(x, xbf, (int)(sz / 8));
    convert_wT<<<dim3(N3_ / 32, D_ / 32), 256, 0, stream>>>(w_qkv, wqkvT, D_, N3_);
    convert_wT<<<dim3(D_ / 32, D_ / 32), 256, 0, stream>>>(w_out, woutT, D_, D_);

    gemm_bt<0><<<dim3(N3_ / 128, (B_ * S_) / 128), 256, 0, stream>>>(
        xbf, wqkvT, b_qkv, q, kk, v, nullptr, D_, N3_);

    attn_mfma<<<dim3(S_ / 64, H_, B_), 256, 0, stream>>>(q, kk, v, mask, ctx);

    gemm_bt<1><<<dim3(D_ / 128, (B_ * S_) / 128), 256, 0, stream>>>(
        ctx, woutT, b_out, nullptr, nullptr, nullptr, out, D_, D_);
}